// Round 1
// baseline (720.717 us; speedup 1.0000x reference)
//
#include <hip/hip_runtime.h>
#include <math.h>

#define N_NODES 50000
#define N_EDGES 800000
#define D_FEAT  128
#define EPSF    1e-12f

// ---------------- workspace layout (bytes) ----------------
// u2      : 128 f                @ 0
// s       : 50000 f              @ 4096
// row_ptr : 50001 i              @ 208896
// cursor  : 50000 i              @ 413696
// ssrc    : 800000 i             @ 618496
// agg     : 50000*128 f          @ 3818496
#define OFF_U2     0
#define OFF_S      4096
#define OFF_ROWPTR 208896
#define OFF_CURSOR 413696
#define OFF_SSRC   618496
#define OFF_AGG    3818496

// u2[k] = sum_j W_coef[k][j] * W_red[128+j]
__global__ void make_u2_kernel(const float* __restrict__ W_coef,
                               const float* __restrict__ W_red,
                               float* __restrict__ u2) {
    int k = threadIdx.x;  // 128 threads
    float acc = 0.f;
    #pragma unroll 8
    for (int j = 0; j < 128; ++j)
        acc += W_coef[k * 128 + j] * W_red[128 + j];
    u2[k] = acc;
}

// s[v] = dot(h[v], u2) ; one wave per node
__global__ __launch_bounds__(256) void node_score_kernel(
        const float* __restrict__ h, const float* __restrict__ u2,
        float* __restrict__ s) {
    int node = blockIdx.x * 4 + (threadIdx.x >> 6);
    int lane = threadIdx.x & 63;
    if (node >= N_NODES) return;
    const float2* hp = (const float2*)(h + (size_t)node * 128);
    const float2* up = (const float2*)u2;
    float2 hv = hp[lane];
    float2 uv = up[lane];
    float v = hv.x * uv.x + hv.y * uv.y;
    #pragma unroll
    for (int off = 32; off; off >>= 1) v += __shfl_down(v, off);
    if (lane == 0) s[node] = v;
}

__global__ void hist_kernel(const int* __restrict__ dst, int* __restrict__ row_ptr) {
    int e = blockIdx.x * blockDim.x + threadIdx.x;
    if (e < N_EDGES) atomicAdd(&row_ptr[dst[e]], 1);
}

// single-block exclusive scan of row_ptr[0..n-1], writes row_ptr[n] = total
__global__ __launch_bounds__(1024) void scan_kernel(int* __restrict__ data, int n) {
    const int T = 1024, EPT = 8;
    __shared__ int lds[T];
    __shared__ int s_carry;
    if (threadIdx.x == 0) s_carry = 0;
    __syncthreads();
    for (int base = 0; base < n; base += T * EPT) {
        int vals[EPT];
        int idx0 = base + threadIdx.x * EPT;
        int local = 0;
        #pragma unroll
        for (int i = 0; i < EPT; ++i) {
            int id = idx0 + i;
            vals[i] = (id < n) ? data[id] : 0;
            local += vals[i];
        }
        lds[threadIdx.x] = local;
        __syncthreads();
        for (int off = 1; off < T; off <<= 1) {
            int t = (threadIdx.x >= off) ? lds[threadIdx.x - off] : 0;
            __syncthreads();
            lds[threadIdx.x] += t;
            __syncthreads();
        }
        int carry = s_carry;
        int excl = carry + lds[threadIdx.x] - local;
        #pragma unroll
        for (int i = 0; i < EPT; ++i) {
            int id = idx0 + i;
            if (id < n) data[id] = excl;
            excl += vals[i];
        }
        __syncthreads();
        if (threadIdx.x == 0) s_carry = carry + lds[T - 1];
        __syncthreads();
    }
    if (threadIdx.x == 0) data[n] = s_carry;
}

__global__ void scatter_kernel(const int* __restrict__ src, const int* __restrict__ dst,
                               int* __restrict__ cursor, int* __restrict__ ssrc) {
    int e = blockIdx.x * blockDim.x + threadIdx.x;
    if (e < N_EDGES) {
        int p = atomicAdd(&cursor[dst[e]], 1);
        ssrc[p] = src[e];
    }
}

// one wave per node: softmax over incoming edges' s[src], agg = sum alpha * h[src]
__global__ __launch_bounds__(256) void aggregate_kernel(
        const int* __restrict__ row_ptr, const int* __restrict__ ssrc,
        const float* __restrict__ s, const float* __restrict__ h,
        float* __restrict__ agg) {
    int node = blockIdx.x * 4 + (threadIdx.x >> 6);
    int lane = threadIdx.x & 63;
    if (node >= N_NODES) return;
    int beg = row_ptr[node];
    int deg = row_ptr[node + 1] - beg;

    // pass 1: segment max of s[src]
    float m = -INFINITY;
    for (int i = lane; i < deg; i += 64)
        m = fmaxf(m, s[ssrc[beg + i]]);
    #pragma unroll
    for (int off = 32; off; off >>= 1) m = fmaxf(m, __shfl_down(m, off));
    m = __shfl(m, 0);

    // pass 2: weighted accumulate (lane owns features 2*lane, 2*lane+1)
    float2 acc = make_float2(0.f, 0.f);
    float denom = 0.f;
    for (int base = 0; base < deg; base += 64) {
        int cnt = min(64, deg - base);
        int esrc = 0;
        float w_l = 0.f;
        if (lane < cnt) {
            esrc = ssrc[beg + base + lane];
            w_l = __expf(s[esrc] - m);
        }
        for (int j = 0; j < cnt; ++j) {
            int   bsrc = __shfl(esrc, j);
            float w    = __shfl(w_l, j);
            denom += w;
            float2 hv = ((const float2*)(h + (size_t)bsrc * 128))[lane];
            acc.x = fmaf(w, hv.x, acc.x);
            acc.y = fmaf(w, hv.y, acc.y);
        }
    }
    float inv = 1.f / (denom + EPSF);
    ((float2*)(agg + (size_t)node * 128))[lane] = make_float2(acc.x * inv, acc.y * inv);
}

// out[v] = normalize([h[v]@W_node + b_node, agg[v]@W_neigh + b_neigh])
// block: 256 threads, 32-node tile; thread (ty,tx): ty=node row (32), tx covers 16 cols (8)
__global__ __launch_bounds__(256) void gemm_norm_kernel(
        const float* __restrict__ h, const float* __restrict__ agg,
        const float* __restrict__ W_node, const float* __restrict__ b_node,
        const float* __restrict__ W_neigh, const float* __restrict__ b_neigh,
        float* __restrict__ out) {
    __shared__ float h_t[32][132];   // +4 pad: breaks 8-way bank conflict on k-broadcast
    __shared__ float a_t[32][132];
    int node0 = blockIdx.x * 32;

    for (int i = threadIdx.x; i < 1024; i += 256) {  // 1024 float4 per array
        int r = i >> 5;
        int c = i & 31;
        int node = node0 + r;
        float4 hv = make_float4(0.f, 0.f, 0.f, 0.f);
        float4 av = make_float4(0.f, 0.f, 0.f, 0.f);
        if (node < N_NODES) {
            hv = ((const float4*)(h + (size_t)node * 128))[c];
            av = ((const float4*)(agg + (size_t)node * 128))[c];
        }
        h_t[r][c * 4 + 0] = hv.x; h_t[r][c * 4 + 1] = hv.y;
        h_t[r][c * 4 + 2] = hv.z; h_t[r][c * 4 + 3] = hv.w;
        a_t[r][c * 4 + 0] = av.x; a_t[r][c * 4 + 1] = av.y;
        a_t[r][c * 4 + 2] = av.z; a_t[r][c * 4 + 3] = av.w;
    }
    __syncthreads();

    int ty = threadIdx.x >> 3;  // 0..31 node in tile
    int tx = threadIdx.x & 7;   // cols tx*16 .. tx*16+15
    float acc1[16], acc2[16];
    #pragma unroll
    for (int i = 0; i < 16; ++i) { acc1[i] = 0.f; acc2[i] = 0.f; }

    for (int k = 0; k < 128; ++k) {
        float a1 = h_t[ty][k];
        float a2 = a_t[ty][k];
        const float4* wn = (const float4*)(W_node + k * 128) + tx * 4;
        const float4* wg = (const float4*)(W_neigh + k * 128) + tx * 4;
        #pragma unroll
        for (int q = 0; q < 4; ++q) {
            float4 w1 = wn[q];
            float4 w2 = wg[q];
            acc1[q * 4 + 0] = fmaf(a1, w1.x, acc1[q * 4 + 0]);
            acc1[q * 4 + 1] = fmaf(a1, w1.y, acc1[q * 4 + 1]);
            acc1[q * 4 + 2] = fmaf(a1, w1.z, acc1[q * 4 + 2]);
            acc1[q * 4 + 3] = fmaf(a1, w1.w, acc1[q * 4 + 3]);
            acc2[q * 4 + 0] = fmaf(a2, w2.x, acc2[q * 4 + 0]);
            acc2[q * 4 + 1] = fmaf(a2, w2.y, acc2[q * 4 + 1]);
            acc2[q * 4 + 2] = fmaf(a2, w2.z, acc2[q * 4 + 2]);
            acc2[q * 4 + 3] = fmaf(a2, w2.w, acc2[q * 4 + 3]);
        }
    }

    // biases + sum of squares
    const float4* bn = (const float4*)b_node + tx * 4;
    const float4* bg = (const float4*)b_neigh + tx * 4;
    float ss = 0.f;
    #pragma unroll
    for (int q = 0; q < 4; ++q) {
        float4 b1 = bn[q], b2 = bg[q];
        acc1[q * 4 + 0] += b1.x; acc1[q * 4 + 1] += b1.y;
        acc1[q * 4 + 2] += b1.z; acc1[q * 4 + 3] += b1.w;
        acc2[q * 4 + 0] += b2.x; acc2[q * 4 + 1] += b2.y;
        acc2[q * 4 + 2] += b2.z; acc2[q * 4 + 3] += b2.w;
        #pragma unroll
        for (int i = 0; i < 4; ++i) {
            ss = fmaf(acc1[q * 4 + i], acc1[q * 4 + i], ss);
            ss = fmaf(acc2[q * 4 + i], acc2[q * 4 + i], ss);
        }
    }
    // reduce ss across the 8 tx threads (aligned 8-lane group within wave)
    ss += __shfl_xor(ss, 1);
    ss += __shfl_xor(ss, 2);
    ss += __shfl_xor(ss, 4);
    float scale = rsqrtf(fmaxf(ss, EPSF));

    int node = node0 + ty;
    if (node < N_NODES) {
        float4* o1 = (float4*)(out + (size_t)node * 256) + tx * 4;
        float4* o2 = (float4*)(out + (size_t)node * 256 + 128) + tx * 4;
        #pragma unroll
        for (int q = 0; q < 4; ++q) {
            o1[q] = make_float4(acc1[q * 4 + 0] * scale, acc1[q * 4 + 1] * scale,
                                acc1[q * 4 + 2] * scale, acc1[q * 4 + 3] * scale);
            o2[q] = make_float4(acc2[q * 4 + 0] * scale, acc2[q * 4 + 1] * scale,
                                acc2[q * 4 + 2] * scale, acc2[q * 4 + 3] * scale);
        }
    }
}

extern "C" void kernel_launch(void* const* d_in, const int* in_sizes, int n_in,
                              void* d_out, int out_size, void* d_ws, size_t ws_size,
                              hipStream_t stream) {
    const float* h       = (const float*)d_in[0];
    const int*   src     = (const int*)d_in[1];
    const int*   dst     = (const int*)d_in[2];
    const float* W_coef  = (const float*)d_in[3];
    // b_coef (d_in[4]) and b_red (d_in[6]) cancel under per-segment softmax shift-invariance
    const float* W_red   = (const float*)d_in[5];
    const float* W_node  = (const float*)d_in[7];
    const float* b_node  = (const float*)d_in[8];
    const float* W_neigh = (const float*)d_in[9];
    const float* b_neigh = (const float*)d_in[10];
    float* out = (float*)d_out;

    char* w = (char*)d_ws;
    float* u2      = (float*)(w + OFF_U2);
    float* s       = (float*)(w + OFF_S);
    int*   row_ptr = (int*)(w + OFF_ROWPTR);
    int*   cursor  = (int*)(w + OFF_CURSOR);
    int*   ssrc    = (int*)(w + OFF_SSRC);
    float* agg     = (float*)(w + OFF_AGG);

    hipMemsetAsync(row_ptr, 0, (N_NODES + 1) * sizeof(int), stream);
    make_u2_kernel<<<1, 128, 0, stream>>>(W_coef, W_red, u2);
    node_score_kernel<<<N_NODES / 4, 256, 0, stream>>>(h, u2, s);
    hist_kernel<<<N_EDGES / 256, 256, 0, stream>>>(dst, row_ptr);
    scan_kernel<<<1, 1024, 0, stream>>>(row_ptr, N_NODES);
    hipMemcpyAsync(cursor, row_ptr, N_NODES * sizeof(int),
                   hipMemcpyDeviceToDevice, stream);
    scatter_kernel<<<N_EDGES / 256, 256, 0, stream>>>(src, dst, cursor, ssrc);
    aggregate_kernel<<<N_NODES / 4, 256, 0, stream>>>(row_ptr, ssrc, s, h, agg);
    gemm_norm_kernel<<<(N_NODES + 31) / 32, 256, 0, stream>>>(
        h, agg, W_node, b_node, W_neigh, b_neigh, out);
}

// Round 2
// 379.990 us; speedup vs baseline: 1.8967x; 1.8967x over previous
//
#include <hip/hip_runtime.h>
#include <math.h>

#define N_NODES 50000
#define N_EDGES 800000
#define D_FEAT  128
#define EPSF    1e-12f

// ---------------- workspace layout (bytes) ----------------
#define OFF_U2     0
#define OFF_S      4096
#define OFF_ROWPTR 208896
#define OFF_CURSOR 413696
#define OFF_SSRC   618496
#define OFF_AGG    3818496

// u2[k] = sum_j W_coef[k][j] * W_red[128+j]
__global__ void make_u2_kernel(const float* __restrict__ W_coef,
                               const float* __restrict__ W_red,
                               float* __restrict__ u2) {
    int k = threadIdx.x;  // 128 threads
    float acc = 0.f;
    #pragma unroll 8
    for (int j = 0; j < 128; ++j)
        acc += W_coef[k * 128 + j] * W_red[128 + j];
    u2[k] = acc;
}

// s[v] = dot(h[v], u2) ; one wave per node
__global__ __launch_bounds__(256) void node_score_kernel(
        const float* __restrict__ h, const float* __restrict__ u2,
        float* __restrict__ s) {
    int node = blockIdx.x * 4 + (threadIdx.x >> 6);
    int lane = threadIdx.x & 63;
    if (node >= N_NODES) return;
    const float2* hp = (const float2*)(h + (size_t)node * 128);
    const float2* up = (const float2*)u2;
    float2 hv = hp[lane];
    float2 uv = up[lane];
    float v = hv.x * uv.x + hv.y * uv.y;
    #pragma unroll
    for (int off = 32; off; off >>= 1) v += __shfl_down(v, off);
    if (lane == 0) s[node] = v;
}

__global__ void hist_kernel(const int* __restrict__ dst, int* __restrict__ row_ptr) {
    int e = blockIdx.x * blockDim.x + threadIdx.x;
    if (e < N_EDGES) atomicAdd(&row_ptr[dst[e]], 1);
}

// single-block exclusive scan of row_ptr[0..n-1], writes row_ptr[n] = total
__global__ __launch_bounds__(1024) void scan_kernel(int* __restrict__ data, int n) {
    const int T = 1024, EPT = 8;
    __shared__ int lds[T];
    __shared__ int s_carry;
    if (threadIdx.x == 0) s_carry = 0;
    __syncthreads();
    for (int base = 0; base < n; base += T * EPT) {
        int vals[EPT];
        int idx0 = base + threadIdx.x * EPT;
        int local = 0;
        #pragma unroll
        for (int i = 0; i < EPT; ++i) {
            int id = idx0 + i;
            vals[i] = (id < n) ? data[id] : 0;
            local += vals[i];
        }
        lds[threadIdx.x] = local;
        __syncthreads();
        for (int off = 1; off < T; off <<= 1) {
            int t = (threadIdx.x >= off) ? lds[threadIdx.x - off] : 0;
            __syncthreads();
            lds[threadIdx.x] += t;
            __syncthreads();
        }
        int carry = s_carry;
        int excl = carry + lds[threadIdx.x] - local;
        #pragma unroll
        for (int i = 0; i < EPT; ++i) {
            int id = idx0 + i;
            if (id < n) data[id] = excl;
            excl += vals[i];
        }
        __syncthreads();
        if (threadIdx.x == 0) s_carry = carry + lds[T - 1];
        __syncthreads();
    }
    if (threadIdx.x == 0) data[n] = s_carry;
}

__global__ void scatter_kernel(const int* __restrict__ src, const int* __restrict__ dst,
                               int* __restrict__ cursor, int* __restrict__ ssrc) {
    int e = blockIdx.x * blockDim.x + threadIdx.x;
    if (e < N_EDGES) {
        int p = atomicAdd(&cursor[dst[e]], 1);
        ssrc[p] = src[e];
    }
}

// one wave per node: softmax over incoming edges' s[src], agg = sum alpha * h[src]
__global__ __launch_bounds__(256) void aggregate_kernel(
        const int* __restrict__ row_ptr, const int* __restrict__ ssrc,
        const float* __restrict__ s, const float* __restrict__ h,
        float* __restrict__ agg) {
    int node = blockIdx.x * 4 + (threadIdx.x >> 6);
    int lane = threadIdx.x & 63;
    if (node >= N_NODES) return;
    int beg = row_ptr[node];
    int deg = row_ptr[node + 1] - beg;

    // pass 1: segment max of s[src]
    float m = -INFINITY;
    for (int i = lane; i < deg; i += 64)
        m = fmaxf(m, s[ssrc[beg + i]]);
    #pragma unroll
    for (int off = 32; off; off >>= 1) m = fmaxf(m, __shfl_down(m, off));
    m = __shfl(m, 0);

    // pass 2: weighted accumulate (lane owns features 2*lane, 2*lane+1)
    float2 acc = make_float2(0.f, 0.f);
    float denom = 0.f;
    for (int base = 0; base < deg; base += 64) {
        int cnt = min(64, deg - base);
        int esrc = 0;
        float w_l = 0.f;
        if (lane < cnt) {
            esrc = ssrc[beg + base + lane];
            w_l = __expf(s[esrc] - m);
        }
        for (int j = 0; j < cnt; ++j) {
            int   bsrc = __shfl(esrc, j);
            float w    = __shfl(w_l, j);
            denom += w;
            float2 hv = ((const float2*)(h + (size_t)bsrc * 128))[lane];
            acc.x = fmaf(w, hv.x, acc.x);
            acc.y = fmaf(w, hv.y, acc.y);
        }
    }
    float inv = 1.f / (denom + EPSF);
    ((float2*)(agg + (size_t)node * 128))[lane] = make_float2(acc.x * inv, acc.y * inv);
}

// out[v] = normalize([h[v]@W_node + b_node, agg[v]@W_neigh + b_neigh])
// Tile: 64 nodes/block, 256 threads. ty=tid>>3 in [0,32) owns rows {ty, ty+32};
// tx=tid&7 owns cols {4*tx+32*q : q=0..3} in each 128-col half.
// Weights staged in LDS in K-chunks of 32 (loaded once per block per chunk,
// ds_read_b128 with 8-way broadcast on disjoint bank quads -> conflict-free).
#define KC 32
__global__ __launch_bounds__(256) void gemm_norm_kernel(
        const float* __restrict__ h, const float* __restrict__ agg,
        const float* __restrict__ W_node, const float* __restrict__ b_node,
        const float* __restrict__ W_neigh, const float* __restrict__ b_neigh,
        float* __restrict__ out) {
    __shared__ float wn_s[KC * 128];      // 16 KB
    __shared__ float wg_s[KC * 128];      // 16 KB
    __shared__ float h_s[64 * 36];        // 9 KB (stride 36: pad vs bank alias)
    __shared__ float a_s[64 * 36];        // 9 KB
    const int tid = threadIdx.x;
    const int tx = tid & 7;
    const int ty = tid >> 3;              // rows ty and ty+32
    const int node0 = blockIdx.x * 64;

    float acc1[2][16], acc2[2][16];
    #pragma unroll
    for (int r = 0; r < 2; ++r)
        #pragma unroll
        for (int i = 0; i < 16; ++i) { acc1[r][i] = 0.f; acc2[r][i] = 0.f; }

    for (int kc = 0; kc < 128; kc += KC) {
        __syncthreads();   // previous chunk's reads done before overwrite
        // stage weights: rows kc..kc+KC-1 are a contiguous 16 KB block each
        {
            const float4* wn_g = (const float4*)(W_node + kc * 128);
            const float4* wg_g = (const float4*)(W_neigh + kc * 128);
            float4* wn_d = (float4*)wn_s;
            float4* wg_d = (float4*)wg_s;
            #pragma unroll
            for (int it = 0; it < 4; ++it) {
                int i = tid + it * 256;   // 1024 float4 per matrix
                wn_d[i] = wn_g[i];
                wg_d[i] = wg_g[i];
            }
        }
        // stage A chunk: 64 rows x KC cols (8 float4 per row per matrix)
        #pragma unroll
        for (int it = 0; it < 2; ++it) {
            int i = tid + it * 256;       // 512 float4 per matrix
            int r = i >> 3, c = i & 7;
            int node = node0 + r;
            float4 hv = make_float4(0.f, 0.f, 0.f, 0.f);
            float4 av = make_float4(0.f, 0.f, 0.f, 0.f);
            if (node < N_NODES) {
                hv = *(const float4*)(h   + (size_t)node * 128 + kc + c * 4);
                av = *(const float4*)(agg + (size_t)node * 128 + kc + c * 4);
            }
            *(float4*)(h_s + r * 36 + c * 4) = hv;
            *(float4*)(a_s + r * 36 + c * 4) = av;
        }
        __syncthreads();

        #pragma unroll 4
        for (int k = 0; k < KC; ++k) {
            float a1_0 = h_s[ty * 36 + k];
            float a1_1 = h_s[(ty + 32) * 36 + k];
            float a2_0 = a_s[ty * 36 + k];
            float a2_1 = a_s[(ty + 32) * 36 + k];
            const float4* wrow_n = (const float4*)(wn_s + k * 128);
            const float4* wrow_g = (const float4*)(wg_s + k * 128);
            #pragma unroll
            for (int q = 0; q < 4; ++q) {
                float4 w1 = wrow_n[tx + 8 * q];   // cols 4*tx+32*q .. +3
                float4 w2 = wrow_g[tx + 8 * q];
                acc1[0][q*4+0] = fmaf(a1_0, w1.x, acc1[0][q*4+0]);
                acc1[0][q*4+1] = fmaf(a1_0, w1.y, acc1[0][q*4+1]);
                acc1[0][q*4+2] = fmaf(a1_0, w1.z, acc1[0][q*4+2]);
                acc1[0][q*4+3] = fmaf(a1_0, w1.w, acc1[0][q*4+3]);
                acc1[1][q*4+0] = fmaf(a1_1, w1.x, acc1[1][q*4+0]);
                acc1[1][q*4+1] = fmaf(a1_1, w1.y, acc1[1][q*4+1]);
                acc1[1][q*4+2] = fmaf(a1_1, w1.z, acc1[1][q*4+2]);
                acc1[1][q*4+3] = fmaf(a1_1, w1.w, acc1[1][q*4+3]);
                acc2[0][q*4+0] = fmaf(a2_0, w2.x, acc2[0][q*4+0]);
                acc2[0][q*4+1] = fmaf(a2_0, w2.y, acc2[0][q*4+1]);
                acc2[0][q*4+2] = fmaf(a2_0, w2.z, acc2[0][q*4+2]);
                acc2[0][q*4+3] = fmaf(a2_0, w2.w, acc2[0][q*4+3]);
                acc2[1][q*4+0] = fmaf(a2_1, w2.x, acc2[1][q*4+0]);
                acc2[1][q*4+1] = fmaf(a2_1, w2.y, acc2[1][q*4+1]);
                acc2[1][q*4+2] = fmaf(a2_1, w2.z, acc2[1][q*4+2]);
                acc2[1][q*4+3] = fmaf(a2_1, w2.w, acc2[1][q*4+3]);
            }
        }
    }

    // epilogue: bias, sum-sq, cross-tx reduce, normalize, store
    float ss[2] = {0.f, 0.f};
    #pragma unroll
    for (int q = 0; q < 4; ++q) {
        float4 b1 = *(const float4*)(b_node  + 4 * tx + 32 * q);
        float4 b2 = *(const float4*)(b_neigh + 4 * tx + 32 * q);
        #pragma unroll
        for (int r = 0; r < 2; ++r) {
            acc1[r][q*4+0] += b1.x; acc1[r][q*4+1] += b1.y;
            acc1[r][q*4+2] += b1.z; acc1[r][q*4+3] += b1.w;
            acc2[r][q*4+0] += b2.x; acc2[r][q*4+1] += b2.y;
            acc2[r][q*4+2] += b2.z; acc2[r][q*4+3] += b2.w;
            #pragma unroll
            for (int i = 0; i < 4; ++i) {
                ss[r] = fmaf(acc1[r][q*4+i], acc1[r][q*4+i], ss[r]);
                ss[r] = fmaf(acc2[r][q*4+i], acc2[r][q*4+i], ss[r]);
            }
        }
    }
    #pragma unroll
    for (int r = 0; r < 2; ++r) {
        ss[r] += __shfl_xor(ss[r], 1);
        ss[r] += __shfl_xor(ss[r], 2);
        ss[r] += __shfl_xor(ss[r], 4);
    }
    #pragma unroll
    for (int r = 0; r < 2; ++r) {
        int node = node0 + ty + r * 32;
        if (node < N_NODES) {
            float scale = rsqrtf(fmaxf(ss[r], EPSF));
            float4* o1 = (float4*)(out + (size_t)node * 256);
            float4* o2 = (float4*)(out + (size_t)node * 256 + 128);
            #pragma unroll
            for (int q = 0; q < 4; ++q) {
                o1[tx + 8 * q] = make_float4(acc1[r][q*4+0] * scale, acc1[r][q*4+1] * scale,
                                             acc1[r][q*4+2] * scale, acc1[r][q*4+3] * scale);
                o2[tx + 8 * q] = make_float4(acc2[r][q*4+0] * scale, acc2[r][q*4+1] * scale,
                                             acc2[r][q*4+2] * scale, acc2[r][q*4+3] * scale);
            }
        }
    }
}

extern "C" void kernel_launch(void* const* d_in, const int* in_sizes, int n_in,
                              void* d_out, int out_size, void* d_ws, size_t ws_size,
                              hipStream_t stream) {
    const float* h       = (const float*)d_in[0];
    const int*   src     = (const int*)d_in[1];
    const int*   dst     = (const int*)d_in[2];
    const float* W_coef  = (const float*)d_in[3];
    // b_coef (d_in[4]) and b_red (d_in[6]) cancel under per-segment softmax shift-invariance
    const float* W_red   = (const float*)d_in[5];
    const float* W_node  = (const float*)d_in[7];
    const float* b_node  = (const float*)d_in[8];
    const float* W_neigh = (const float*)d_in[9];
    const float* b_neigh = (const float*)d_in[10];
    float* out = (float*)d_out;

    char* w = (char*)d_ws;
    float* u2      = (float*)(w + OFF_U2);
    float* s       = (float*)(w + OFF_S);
    int*   row_ptr = (int*)(w + OFF_ROWPTR);
    int*   cursor  = (int*)(w + OFF_CURSOR);
    int*   ssrc    = (int*)(w + OFF_SSRC);
    float* agg     = (float*)(w + OFF_AGG);

    hipMemsetAsync(row_ptr, 0, (N_NODES + 1) * sizeof(int), stream);
    make_u2_kernel<<<1, 128, 0, stream>>>(W_coef, W_red, u2);
    node_score_kernel<<<N_NODES / 4, 256, 0, stream>>>(h, u2, s);
    hist_kernel<<<N_EDGES / 256, 256, 0, stream>>>(dst, row_ptr);
    scan_kernel<<<1, 1024, 0, stream>>>(row_ptr, N_NODES);
    hipMemcpyAsync(cursor, row_ptr, N_NODES * sizeof(int),
                   hipMemcpyDeviceToDevice, stream);
    scatter_kernel<<<N_EDGES / 256, 256, 0, stream>>>(src, dst, cursor, ssrc);
    aggregate_kernel<<<N_NODES / 4, 256, 0, stream>>>(row_ptr, ssrc, s, h, agg);
    gemm_norm_kernel<<<(N_NODES + 63) / 64, 256, 0, stream>>>(
        h, agg, W_node, b_node, W_neigh, b_neigh, out);
}